// Round 15
// baseline (316.147 us; speedup 1.0000x reference)
//
#include <hip/hip_runtime.h>

#define EMB 128
#define NN 50000
#define BB 1024
#define LL 50
#define NBK 49     // ceil(NN/1024) buckets
#define NEB 512    // emit/count chunks
#define NCONV 2048 // prep convert blocks; blocks >= NCONV do wcomb/uf folds

typedef float f32x4 __attribute__((ext_vector_type(4)));
typedef float f32x2 __attribute__((ext_vector_type(2)));
typedef unsigned short u16;
typedef unsigned int u32;
typedef unsigned long long u64;
typedef u16 u16x4 __attribute__((ext_vector_type(4)));
typedef u32 u32x4 __attribute__((ext_vector_type(4)));
typedef short bf16x8 __attribute__((ext_vector_type(8)));   // 8 bf16 in 4 VGPRs

__device__ __forceinline__ float u2f(u16 u) {
    union { unsigned int i; float f; } v; v.i = ((unsigned int)u) << 16; return v.f;
}
__device__ __forceinline__ u16 f2b(float f) {
    union { float f; unsigned int i; } v; v.f = f;
    unsigned int i = v.i;
    return (u16)((i + 0x7FFFu + ((i >> 16) & 1u)) >> 16);   // RNE
}
__device__ __forceinline__ float lo2f(u32 w) { return u2f((u16)(w & 0xffffu)); }
__device__ __forceinline__ float hi2f(u32 w) { return u2f((u16)(w >> 16)); }
__device__ __forceinline__ float sigmoidf_(float x) { return 1.f / (1.f + __expf(-x)); }
__device__ __forceinline__ float tanhf_(float x) {
    float e = __expf(-2.f * x);
    return (1.f - e) / (1.f + e);
}

// ============ prep: converts + per-(chunk,bucket) counts + Wcomb/uf folds ============
// uf[d][12]: 0..2 = u1{r,i,n}, 3..5 = u2{r,i,n}, 6 = u3r+b_hh[d], 7 = u3i+b_hh[128+d],
//            8 = u3n, 9 = b_hh[256+d] (bnh), 10..11 = 0.
__global__ __launch_bounds__(256) void prep_kernel(
    const float* __restrict__ emb, const float* __restrict__ A, const float* __restrict__ D,
    const float* __restrict__ whh,
    u16* __restrict__ emb_bf, u16* __restrict__ A_bf, u16* __restrict__ D_bf,
    u16* __restrict__ whh_bf,
    const int* __restrict__ rowi, int* __restrict__ bcnt,
    const float* __restrict__ w_ih, const float* __restrict__ W_in, const float* __restrict__ W_out,
    const float* __restrict__ b_in, const float* __restrict__ b_out,
    const float* __restrict__ b_iah, const float* __restrict__ b_oah, const float* __restrict__ b_ih,
    const float* __restrict__ b_hh,
    u16* __restrict__ WcT_bf, float* __restrict__ uf,
    int E, int chunk)
{
    __shared__ int lc[NBK];
    __shared__ float wrow[256];
    __shared__ float red[3][256];
    int tid = threadIdx.x;

    if (blockIdx.x >= NCONV) {
        // ---- wcomb + uf block: d = blockIdx.x - NCONV in [0,384) ----
        int d = blockIdx.x - NCONV;
        int c = tid;
        wrow[c] = w_ih[d * 256 + c];
        __syncthreads();
        const float* W = (c < 128) ? W_in : W_out;
        const float* wr = wrow + ((c < 128) ? 0 : 128);
        int cc = c & 127;
        float acc = 0.f;
#pragma unroll 4
        for (int j = 0; j < 128; j++) acc += wr[j] * W[j * 128 + cc];
        WcT_bf[d * 256 + c] = f2b(acc);
        // uf partials (coalesced: all of w_ih row d already in LDS)
        float p1 = (c < 128) ? b_in[c] * wrow[c] : 0.f;
        float p2 = (c >= 128) ? b_out[cc] * wrow[c] : 0.f;
        float p3 = (c < 128) ? b_iah[c] * wrow[c] : b_oah[cc] * wrow[c];
        red[0][c] = p1; red[1][c] = p2; red[2][c] = p3;
        __syncthreads();
        for (int off = 128; off > 0; off >>= 1) {
            if (c < off) {
                red[0][c] += red[0][c + off];
                red[1][c] += red[1][c + off];
                red[2][c] += red[2][c + off];
            }
            __syncthreads();
        }
        if (c == 0) {
            int g = d >> 7, dd = d & 127;
            float u1v = red[0][0];
            float u2v = red[1][0];
            float u3v = red[2][0] + b_ih[d];
            uf[dd * 12 + g] = u1v;
            uf[dd * 12 + 3 + g] = u2v;
            if (g == 0)      uf[dd * 12 + 6] = u3v + b_hh[dd];
            else if (g == 1) uf[dd * 12 + 7] = u3v + b_hh[128 + dd];
            else {
                uf[dd * 12 + 8]  = u3v;
                uf[dd * 12 + 9]  = b_hh[256 + dd];
                uf[dd * 12 + 10] = 0.f;
                uf[dd * 12 + 11] = 0.f;
            }
        }
        return;
    }

    int gid = blockIdx.x * 256 + tid;
    int stride = NCONV * 256;
    if (blockIdx.x < NEB) {
        if (tid < NBK) lc[tid] = 0;
        __syncthreads();
        int beg = blockIdx.x * chunk, end = min(E, beg + chunk);
        for (int e = beg + tid; e < end; e += 256)
            atomicAdd(&lc[rowi[e] >> 10], 1);
        __syncthreads();
        if (tid < NBK) bcnt[blockIdx.x * NBK + tid] = lc[tid];
    }
    for (int i = gid; i < 1600000; i += stride) {
        f32x4 v = *(const f32x4*)(emb + (size_t)i * 4);
        u16x4 p;
#pragma unroll
        for (int t = 0; t < 4; t++) p[t] = f2b(v[t]);
        *(u16x4*)(emb_bf + (size_t)i * 4) = p;
    }
    for (int i = gid; i < 2146304; i += stride) {
        const float* s; u16* d; int off;
        if (i < 1048576)      { s = A;   d = A_bf;   off = i; }
        else if (i < 2097152) { s = D;   d = D_bf;   off = i - 1048576; }
        else                  { s = whh; d = whh_bf; off = i - 2097152; }
        d[off] = f2b(s[off]);
    }
}

// per-bucket exclusive scan over chunks -> LOCAL bases + bucket totals
__global__ __launch_bounds__(512) void bktscan_kernel(
    const int* __restrict__ bcnt, int* __restrict__ sofs, int* __restrict__ btot)
{
    __shared__ int ps[512];
    int k = blockIdx.x, t = threadIdx.x;
    int c = bcnt[t * NBK + k];
    ps[t] = c; __syncthreads();
    for (int off = 1; off < 512; off <<= 1) {
        int v = (t >= off) ? ps[t - off] : 0;
        __syncthreads();
        ps[t] += v; __syncthreads();
    }
    sofs[t * NBK + k] = ps[t] - c;
    if (t == 511) btot[k] = ps[511];
}

__global__ __launch_bounds__(64) void btotal_kernel(
    const int* __restrict__ btot, int* __restrict__ bofs, int E)
{
    if (threadIdx.x == 0) {
        int run = 0;
        for (int k = 0; k < NBK; k++) { bofs[k] = run; run += btot[k]; }
        bofs[NBK] = E;
    }
}

__global__ __launch_bounds__(256) void emit_kernel(
    const int* __restrict__ rowi, const int* __restrict__ coli, const float* __restrict__ val,
    const int* __restrict__ sofs, const int* __restrict__ bofs,
    u64* __restrict__ egs, int E, int chunk)
{
    __shared__ int cur[NBK];
    int b = blockIdx.x, tid = threadIdx.x;
    if (tid < NBK) cur[tid] = bofs[tid] + sofs[b * NBK + tid];
    __syncthreads();
    int beg = b * chunk, end = min(E, beg + chunk);
    for (int e = beg + tid; e < end; e += 256) {
        int r = rowi[e];
        int slot = atomicAdd(&cur[r >> 10], 1);
        u64 entry = ((u64)(u32)(r & 1023) << 32)
                  | (u64)((u32)(u16)coli[e] | ((u32)f2b(val[e]) << 16));
        egs[slot] = entry;
    }
}

__global__ __launch_bounds__(1024) void binsort2_kernel(
    const u64* __restrict__ egs, const int* __restrict__ bofs,
    int* __restrict__ row_ptr, u32* __restrict__ eg, int E)
{
    __shared__ int cnt_s[1024];
    __shared__ int ps[1024];
    int k = blockIdx.x, tid = threadIdx.x;
    int r0 = k << 10;
    int beg = bofs[k], end = bofs[k + 1];
    cnt_s[tid] = 0;
    __syncthreads();
    for (int i = beg + tid; i < end; i += 1024)
        atomicAdd(&cnt_s[(int)(egs[i] >> 32)], 1);
    __syncthreads();
    int v = cnt_s[tid];
    ps[tid] = v; __syncthreads();
    for (int off = 1; off < 1024; off <<= 1) {
        int t = (tid >= off) ? ps[tid - off] : 0;
        __syncthreads();
        ps[tid] += t; __syncthreads();
    }
    int ex = beg + ps[tid] - v;
    if (r0 + tid <= NN) row_ptr[r0 + tid] = ex;
    if (k == NBK - 1 && tid == 1023) row_ptr[NN] = E;
    cnt_s[tid] = ex;
    __syncthreads();
    for (int i = beg + tid; i < end; i += 1024) {
        u64 entry = egs[i];
        int rlo = (int)(entry >> 32);
        int p = atomicAdd(&cnt_s[rlo], 1);
        eg[p] = (u32)entry;
    }
}

// One wave per row. 64 lanes = 4 edge-groups x 16 feature-blocks.
template<int FUSE>
__global__ __launch_bounds__(256) void gatherb_kernel(
    const int* __restrict__ row_ptr, const u32* __restrict__ eg,
    const u16* __restrict__ src, const float* __restrict__ emb0,
    u16* __restrict__ dst_bf, float* __restrict__ dst_f)
{
    int wave = threadIdx.x >> 6;
    int lane = threadIdx.x & 63;
    int g  = lane >> 4;          // edge slot within chunk-of-4
    int fl = lane & 15;          // feature block: features fl*8 .. fl*8+7
    int r = blockIdx.x * 4 + wave;
    if (r >= NN) return;
    int beg = row_ptr[r], end = row_ptr[r + 1];

    float acc[8];
#pragma unroll
    for (int t = 0; t < 8; t++) acc[t] = 0.f;

    if (beg < end) {
        int last = end - 1;
        int npair = (end - beg + 7) >> 3;
        u32 pkA = eg[min(beg + g, last)];
        u32 pkB = eg[min(beg + 4 + g, last)];
        float vA = (beg + g     < end) ? u2f((u16)(pkA >> 16)) : 0.f;
        float vB = (beg + 4 + g < end) ? u2f((u16)(pkB >> 16)) : 0.f;
        u32x4 xA = *(const u32x4*)(src + ((pkA & 0xffffu) << 7) + (fl << 3));
        u32x4 xB = *(const u32x4*)(src + ((pkB & 0xffffu) << 7) + (fl << 3));
        pkA = eg[min(beg + 8  + g, last)];
        pkB = eg[min(beg + 12 + g, last)];

        int e = beg;
        for (int p = 0; p < npair; p++) {
            float cvA = vA, cvB = vB;
            u32x4 cxA = xA, cxB = xB;
            int eN = e + 8;
            vA = (eN + g     < end) ? u2f((u16)(pkA >> 16)) : 0.f;
            vB = (eN + 4 + g < end) ? u2f((u16)(pkB >> 16)) : 0.f;
            xA = *(const u32x4*)(src + ((pkA & 0xffffu) << 7) + (fl << 3));
            xB = *(const u32x4*)(src + ((pkB & 0xffffu) << 7) + (fl << 3));
            int eS = e + 16;
            pkA = eg[min(eS + g, last)];
            pkB = eg[min(eS + 4 + g, last)];
#pragma unroll
            for (int t = 0; t < 4; t++) {
                acc[2 * t]     += cvA * lo2f(cxA[t]);
                acc[2 * t + 1] += cvA * hi2f(cxA[t]);
            }
#pragma unroll
            for (int t = 0; t < 4; t++) {
                acc[2 * t]     += cvB * lo2f(cxB[t]);
                acc[2 * t + 1] += cvB * hi2f(cxB[t]);
            }
            e += 8;
        }
    }

#pragma unroll
    for (int t = 0; t < 8; t++) {
        acc[t] += __shfl_xor(acc[t], 16);
        acc[t] += __shfl_xor(acc[t], 32);
    }

    if (lane < 16) {
        if (FUSE) {
            u32x4 s = *(const u32x4*)(src + ((u32)r << 7) + (lane << 3));
            const float* e0p = emb0 + ((size_t)r << 7) + (lane << 3);
            f32x4 e0a = *(const f32x4*)e0p;
            f32x4 e0b = *(const f32x4*)(e0p + 4);
            f32x4 o0, o1;
#pragma unroll
            for (int t = 0; t < 2; t++) {
                o0[2 * t]     = acc[2 * t]     + e0a[2 * t]     + lo2f(s[t]);
                o0[2 * t + 1] = acc[2 * t + 1] + e0a[2 * t + 1] + hi2f(s[t]);
                o1[2 * t]     = acc[4 + 2 * t]     + e0b[2 * t]     + lo2f(s[2 + t]);
                o1[2 * t + 1] = acc[4 + 2 * t + 1] + e0b[2 * t + 1] + hi2f(s[2 + t]);
            }
            float* dp = dst_f + ((size_t)r << 7) + (lane << 3);
            *(f32x4*)dp = o0;
            *(f32x4*)(dp + 4) = o1;
        } else {
            u32x4 w;
#pragma unroll
            for (int t = 0; t < 4; t++)
                w[t] = (u32)f2b(acc[2 * t]) | ((u32)f2b(acc[2 * t + 1]) << 16);
            *(u32x4*)(dst_bf + ((size_t)r << 7) + (lane << 3)) = w;
        }
    }
}

// ================= Part 2: LineConv (bf16 MFMA chain) =================
__global__ __launch_bounds__(128) void sess_pool_kernel(
    const int* __restrict__ items, const float* __restrict__ emb,
    const float* __restrict__ slen, float* __restrict__ sess, u16* __restrict__ sessT)
{
    int b = blockIdx.x, d = threadIdx.x;
    const int* it = items + b * LL;
    float acc = 0.f;
    for (int l = 0; l < LL; l++) {
        int idx = it[l];
        if (idx > 0) acc += emb[(size_t)(idx - 1) * EMB + d];
    }
    float v = acc / slen[b];
    sess[b * EMB + d] = v;
    sessT[d * BB + b] = f2b(v);
}

// C[1024,128] = M_bf @ Xt_bf^T. 64 blocks x 4 waves; wave owns (16-row tile, 2 col-tiles).
// FADD: epilogue writes C_f = acc + add1 + add2 (fuses the final out1 sum).
template<int WT, int WF, int FADD>
__global__ __launch_bounds__(256) void mm_mfma_kernel(
    const u16* __restrict__ M_bf, const u16* __restrict__ Xt_bf,
    u16* __restrict__ Ct_bf, float* __restrict__ C_f,
    const float* __restrict__ add1, const float* __restrict__ add2)
{
    int tid = threadIdx.x;
    int wv = tid >> 6, lane = tid & 63, cl = lane & 15, kg = lane >> 4;
    int rbase = blockIdx.x * 16;
    f32x4 acc[2];
    acc[0] = (f32x4)0.f; acc[1] = (f32x4)0.f;
    const u16* arow = M_bf + (size_t)(rbase + cl) * BB + kg * 8;
    const u16* brow = Xt_bf + (size_t)(wv * 32 + cl) * BB + kg * 8;
#pragma unroll 4
    for (int k0 = 0; k0 < BB; k0 += 32) {
        bf16x8 a  = *(const bf16x8*)(arow + k0);
        bf16x8 b0 = *(const bf16x8*)(brow + k0);
        bf16x8 b1 = *(const bf16x8*)(brow + (size_t)16 * BB + k0);
        acc[0] = __builtin_amdgcn_mfma_f32_16x16x32_bf16(a, b0, acc[0], 0, 0, 0);
        acc[1] = __builtin_amdgcn_mfma_f32_16x16x32_bf16(a, b1, acc[1], 0, 0, 0);
    }
#pragma unroll
    for (int nt = 0; nt < 2; nt++) {
        int col = (wv * 2 + nt) * 16 + cl;
#pragma unroll
        for (int j = 0; j < 4; j++) {
            int row = rbase + kg * 4 + j;
            size_t ix = (size_t)row * EMB + col;
            if (WF) {
                float v = acc[nt][j];
                if (FADD) v += add1[ix] + add2[ix];
                C_f[ix] = v;
            }
            if (WT) Ct_bf[(size_t)col * BB + row] = f2b(acc[nt][j]);
        }
    }
}

// ========== Part 3: GNN, reassociated; Phase-2 row-split, NATURAL allocation ==========
// Phase 0: stage hidden (Hs swz + HsT strided) and A_cat (As swz) once; rowsums -> rcs.
// Phase 1: M2 = A_cat @ hidden  ([64 x 256], K=64) -> M2s (overlays As+HsT).
// Phase 2: TWO sequential row-half passes (rp, #pragma unroll 1); 32 acc f32/lane.
// NO launch_bounds min-waves (R7/R9: caps below demand => catastrophic spill). Goal:
// natural VGPR+AGPR <= 128 (R13's identical phase-2 body compiled to 72) -> 4 waves/SIMD
// -> 2 independent 8-wave blocks/CU with zero duplicated staging.
__global__ __launch_bounds__(512) void gnn_tail_kernel(
    const float* __restrict__ hidden,
    const float* __restrict__ A_gnn, const int* __restrict__ alias_pos,
    const u16* __restrict__ WcT_bf, const u16* __restrict__ w_hh_bf,
    const float* __restrict__ uf,
    float* __restrict__ hy)
{
    __shared__ __attribute__((aligned(16))) u16 smem[25600];   // 51.2 KB
    u16* Hs  = smem;            // [64][128] bf16 swz
    u16* As  = smem + 8192;     // [64][128] bf16 swz (cols 0-63 A_in, 64-127 A_out)
    u16* HsT = smem + 16384;    // [128][72] bf16 strided (144B rows)
    u16* M2s = smem + 8192;     // [64][256] bf16 swz, overlays As+HsT[:8192] after Phase 1
    __shared__ float rcs[64][2];

    int b = blockIdx.x;
    int tid = threadIdx.x;
    int wv = tid >> 6, lane = tid & 63, cl = lane & 15, kg = lane >> 4;

    // ---- Phase 0: prefetch A_io + hidden into regs, then write LDS ----
    int pr_row[4], pr_c4[4], ppos[4];
#pragma unroll
    for (int it = 0; it < 4; it++) {
        int i = tid + it * 512;
        pr_row[it] = i >> 5; pr_c4[it] = i & 31;
        ppos[it] = (pr_row[it] < LL) ? alias_pos[b * LL + pr_row[it]] : 0;
    }
    float av[4][4];
#pragma unroll
    for (int it = 0; it < 4; it++) {
        const float* ar = A_gnn + ((size_t)b * LL + ppos[it]) * (2 * LL);
#pragma unroll
        for (int t = 0; t < 4; t++) {
            int jp = pr_c4[it] * 4 + t;
            int col = (jp < 64) ? jp : (50 + (jp - 64));
            int ok = (pr_row[it] < LL) && ((jp < 64) ? (jp < LL) : ((jp - 64) < LL));
            av[it][t] = ok ? ar[col] : 0.f;
        }
    }
    const float* hsrc = hidden + (size_t)b * LL * EMB;
#pragma unroll
    for (int it = 0; it < 4; it++) {
        u16x4 p;
#pragma unroll
        for (int t = 0; t < 4; t++) p[t] = f2b(av[it][t]);
        *(u16x4*)((char*)As + pr_row[it] * 256 + ((pr_c4[it] * 8) ^ ((pr_row[it] & 7) << 4))) = p;
    }
#pragma unroll
    for (int i2 = 0; i2 < 4; i2++) {
        int lin = i2 * 512 + tid;
        int hrow = lin >> 5, hc4 = lin & 31;
        f32x4 v = (hrow < LL) ? *(const f32x4*)(hsrc + hrow * 128 + hc4 * 4) : (f32x4)0.f;
        u16x4 q;
#pragma unroll
        for (int t = 0; t < 4; t++) q[t] = f2b(v[t]);
        *(u16x4*)((char*)Hs + hrow * 256 + ((hc4 * 8) ^ ((hrow & 7) << 4))) = q;
    }
    // HsT: thread handles column c, 4 rows rg*4..rg*4+3 -> single u16x4 write
#pragma unroll
    for (int i2 = 0; i2 < 4; i2++) {
        int idx = i2 * 512 + tid;
        int c = idx & 127, rg = idx >> 7;
        int r0 = rg * 4;
        u16x4 p = (u16x4)0;
#pragma unroll
        for (int k = 0; k < 4; k++) {
            int row = r0 + k;
            p[k] = (row < LL) ? f2b(hsrc[row * 128 + c]) : (u16)0;
        }
        *(u16x4*)&HsT[c * 72 + r0] = p;
    }
    __syncthreads();   // bar1: staging done

    // rowsums (waves 0-1 only; consumed after bar3)
    if (tid < 128) {
        int row = tid >> 1, hf = tid & 1;
        float s = 0.f;
#pragma unroll
        for (int c4 = 0; c4 < 16; c4++) {
            u16x4 v = *(const u16x4*)((const char*)As + row * 256 +
                        ((hf * 128 + c4 * 8) ^ ((row & 7) << 4)));
            s += u2f(v[0]) + u2f(v[1]) + u2f(v[2]) + u2f(v[3]);
        }
        rcs[row][hf] = s;
    }

    // ---- Phase 1: M2 = A_cat @ hidden; wave = (h = wv>>2, ct = wv&3) ----
    {
        int h = wv >> 2, ct = wv & 3;
        f32x4 m2acc[4][2];
#pragma unroll
        for (int mt = 0; mt < 4; mt++) { m2acc[mt][0] = (f32x4)0.f; m2acc[mt][1] = (f32x4)0.f; }
#pragma unroll
        for (int ks = 0; ks < 2; ks++) {
            bf16x8 bb[2];
#pragma unroll
            for (int nt = 0; nt < 2; nt++) {
                int c = ct * 32 + nt * 16 + cl;
                bb[nt] = *(const bf16x8*)&HsT[c * 72 + ks * 32 + kg * 8];
            }
#pragma unroll
            for (int mt = 0; mt < 4; mt++) {
                int mr = mt * 16 + cl;
                bf16x8 aa = *(const bf16x8*)((const char*)As + mr * 256 +
                             ((h * 128 + ks * 64 + kg * 16) ^ ((mr & 7) << 4)));
#pragma unroll
                for (int nt = 0; nt < 2; nt++)
                    m2acc[mt][nt] = __builtin_amdgcn_mfma_f32_16x16x32_bf16(aa, bb[nt], m2acc[mt][nt], 0, 0, 0);
            }
        }
        __syncthreads();   // bar2: all P1 reads (and rcs reads of As) done
#pragma unroll
        for (int mt = 0; mt < 4; mt++)
#pragma unroll
            for (int nt = 0; nt < 2; nt++) {
                int kcol = h * 128 + ct * 32 + nt * 16 + cl;
#pragma unroll
                for (int j = 0; j < 4; j++) {
                    int row = mt * 16 + kg * 4 + j;
                    *(u16*)((char*)M2s + row * 512 + ((kcol * 2) ^ ((row & 7) << 4))) =
                        f2b(m2acc[mt][nt][j]);
                }
            }
    }
    __syncthreads();   // bar3: M2s ready

    // ---- Phase 2: two row-half passes; d = wv*16+cl; 32 acc f32 per pass ----
    int dl = wv * 16 + cl;
#pragma unroll 1
    for (int rp = 0; rp < 2; rp++) {
        f32x4 accR[2], accI[2], accN1[2], accN2[2];
#pragma unroll
        for (int mt = 0; mt < 2; mt++) {
            accR[mt] = (f32x4)0.f; accI[mt] = (f32x4)0.f;
            accN1[mt] = (f32x4)0.f; accN2[mt] = (f32x4)0.f;
        }

#pragma unroll
        for (int ks = 0; ks < 8; ks++) {
            {
                bf16x8 bw = *(const bf16x8*)(WcT_bf + (size_t)dl * 256 + ks * 32 + kg * 8);
#pragma unroll
                for (int mt = 0; mt < 2; mt++) {
                    int mr = rp * 32 + mt * 16 + cl;
                    bf16x8 a = *(const bf16x8*)((const char*)M2s + mr * 512 +
                                 ((ks * 64 + kg * 16) ^ ((mr & 7) << 4)));
                    accR[mt] = __builtin_amdgcn_mfma_f32_16x16x32_bf16(a, bw, accR[mt], 0, 0, 0);
                }
            }
            {
                bf16x8 bw = *(const bf16x8*)(WcT_bf + (size_t)(128 + dl) * 256 + ks * 32 + kg * 8);
#pragma unroll
                for (int mt = 0; mt < 2; mt++) {
                    int mr = rp * 32 + mt * 16 + cl;
                    bf16x8 a = *(const bf16x8*)((const char*)M2s + mr * 512 +
                                 ((ks * 64 + kg * 16) ^ ((mr & 7) << 4)));
                    accI[mt] = __builtin_amdgcn_mfma_f32_16x16x32_bf16(a, bw, accI[mt], 0, 0, 0);
                }
            }
            {
                bf16x8 bw = *(const bf16x8*)(WcT_bf + (size_t)(256 + dl) * 256 + ks * 32 + kg * 8);
#pragma unroll
                for (int mt = 0; mt < 2; mt++) {
                    int mr = rp * 32 + mt * 16 + cl;
                    bf16x8 a = *(const bf16x8*)((const char*)M2s + mr * 512 +
                                 ((ks * 64 + kg * 16) ^ ((mr & 7) << 4)));
                    accN1[mt] = __builtin_amdgcn_mfma_f32_16x16x32_bf16(a, bw, accN1[mt], 0, 0, 0);
                }
            }
        }
#pragma unroll
        for (int ks = 0; ks < 4; ks++) {
            {
                bf16x8 bw = *(const bf16x8*)(w_hh_bf + (size_t)dl * 128 + ks * 32 + kg * 8);
#pragma unroll
                for (int mt = 0; mt < 2; mt++) {
                    int mr = rp * 32 + mt * 16 + cl;
                    bf16x8 a = *(const bf16x8*)((const char*)Hs + mr * 256 +
                                 ((ks * 64 + kg * 16) ^ ((mr & 7) << 4)));
                    accR[mt] = __builtin_amdgcn_mfma_f32_16x16x32_bf16(a, bw, accR[mt], 0, 0, 0);
                }
            }
            {
                bf16x8 bw = *(const bf16x8*)(w_hh_bf + (size_t)(128 + dl) * 128 + ks * 32 + kg * 8);
#pragma unroll
                for (int mt = 0; mt < 2; mt++) {
                    int mr = rp * 32 + mt * 16 + cl;
                    bf16x8 a = *(const bf16x8*)((const char*)Hs + mr * 256 +
                                 ((ks * 64 + kg * 16) ^ ((mr & 7) << 4)));
                    accI[mt] = __builtin_amdgcn_mfma_f32_16x16x32_bf16(a, bw, accI[mt], 0, 0, 0);
                }
            }
            {
                bf16x8 bw = *(const bf16x8*)(w_hh_bf + (size_t)(256 + dl) * 128 + ks * 32 + kg * 8);
#pragma unroll
                for (int mt = 0; mt < 2; mt++) {
                    int mr = rp * 32 + mt * 16 + cl;
                    bf16x8 a = *(const bf16x8*)((const char*)Hs + mr * 256 +
                                 ((ks * 64 + kg * 16) ^ ((mr & 7) << 4)));
                    accN2[mt] = __builtin_amdgcn_mfma_f32_16x16x32_bf16(a, bw, accN2[mt], 0, 0, 0);
                }
            }
        }

        // ---- GRU gates for this pass's rows: loads fenced out of the MFMA region ----
        __builtin_amdgcn_sched_barrier(0);
        {
            const f32x4* ufp = (const f32x4*)(uf + dl * 12);
            f32x4 U0 = ufp[0];   // u1r u1i u1n u2r
            f32x4 U1 = ufp[1];   // u2i u2n u3r' u3i'
            f32x4 U2 = ufp[2];   // u3n bnh 0 0
            float* hyb = hy + (size_t)b * LL * 128 + dl;
#pragma unroll
            for (int mt = 0; mt < 2; mt++)
#pragma unroll
                for (int j = 0; j < 4; j++) {
                    int row = rp * 32 + mt * 16 + kg * 4 + j;
                    if (row >= LL) continue;
                    float cr = rcs[row][0], dr = rcs[row][1];
                    float pr  = accR[mt][j]  + cr * U0[0] + dr * U0[3] + U1[2];
                    float pi  = accI[mt][j]  + cr * U0[1] + dr * U1[0] + U1[3];
                    float pn1 = accN1[mt][j] + cr * U0[2] + dr * U1[1] + U2[0];
                    float pn2 = accN2[mt][j] + U2[1];
                    float rg = sigmoidf_(pr);
                    float ig = sigmoidf_(pi);
                    float ng = tanhf_(pn1 + rg * pn2);
                    u16 hb = *(const u16*)((const char*)Hs + row * 256 + ((dl * 2) ^ ((row & 7) << 4)));
                    float h = u2f(hb);
                    hyb[row * 128] = ng + ig * (h - ng);
                }
        }
    }
}

extern "C" void kernel_launch(void* const* d_in, const int* in_sizes, int n_in,
                              void* d_out, int out_size, void* d_ws, size_t ws_size,
                              hipStream_t stream) {
    (void)n_in; (void)out_size; (void)ws_size;
    const int*   adj_row      = (const int*)d_in[0];
    const int*   adj_col      = (const int*)d_in[1];
    const float* adj_val      = (const float*)d_in[2];
    const float* embedding    = (const float*)d_in[3];
    const int*   session_item = (const int*)d_in[4];
    const float* session_len  = (const float*)d_in[5];
    const float* Dm           = (const float*)d_in[6];
    const float* A_sess       = (const float*)d_in[7];
    const float* A_gnn        = (const float*)d_in[8];
    const int*   alias_pos    = (const int*)d_in[9];
    const float* hidden       = (const float*)d_in[10];
    const float* W_in         = (const float*)d_in[11];
    const float* b_in         = (const float*)d_in[12];
    const float* W_out        = (const float*)d_in[13];
    const float* b_out        = (const float*)d_in[14];
    const float* w_ih         = (const float*)d_in[15];
    const float* b_ih         = (const float*)d_in[16];
    const float* w_hh         = (const float*)d_in[17];
    const float* b_hh         = (const float*)d_in[18];
    const float* b_iah        = (const float*)d_in[19];
    const float* b_oah        = (const float*)d_in[20];
    const int E = in_sizes[0];

    float* out0 = (float*)d_out;
    float* out1 = out0 + 6400000;
    float* out2 = out1 + 131072;

    float* ws = (float*)d_ws;
    u16*  emb_bf  = (u16*)ws;                    // [0, 3.2M) live through gathers
    int*  bcnt  = (int*)(ws + 3200000);          // scratch under accA region
    int*  sofs  = (int*)(ws + 3230000);
    int*  btot  = (int*)(ws + 3260000);
    u16*  accA_bf = (u16*)(ws + 3200000);        // [3.2M, 6.4M) gather<0> out
    u32*  eg    = (u32*)(ws + 6400000);          // [6.4M, 8.0M)
    u64*  egs   = (u64*)(ws + 8000000);          // [8.0M, 11.2M)
    float* sess  = ws + 11200000;
    u16*   sessT = (u16*)(ws + 11350000);
    u16*   t1T   = (u16*)(ws + 11400000);
    u16*   s1T   = (u16*)(ws + 11450000);
    u16*   t2T   = (u16*)(ws + 11500000);
    float* s1    = ws + 11550000;
    u16*   A_bf  = (u16*)(ws + 11850000);
    u16*   D_bf  = (u16*)(ws + 12400000);
    int*   row_ptr = (int*)(ws + 12950000);
    int*   bofs    = row_ptr + NN + 1;
    u16* WcT_bf    = (u16*)(ws + 13107200);      // [384][256] bf16
    u16* w_hh_bf   = WcT_bf + 98304;             // [384][128] bf16
    float* uf      = (float*)(w_hh_bf + 49152);  // [128][12] f32 bias folds

    int chunk = (E + NEB - 1) / NEB;

    // ---- prep: converts + chunked bucket counts + weight/bias folds (tail blocks) ----
    prep_kernel<<<NCONV + 384, 256, 0, stream>>>(embedding, A_sess, Dm, w_hh,
                                          emb_bf, A_bf, D_bf, w_hh_bf,
                                          adj_row, bcnt,
                                          w_ih, W_in, W_out, b_in, b_out, b_iah, b_oah, b_ih, b_hh,
                                          WcT_bf, uf,
                                          E, chunk);

    // ---- Part 1: bucket sort + 2 bf16 gather layers ----
    bktscan_kernel<<<NBK, 512, 0, stream>>>(bcnt, sofs, btot);
    btotal_kernel<<<1, 64, 0, stream>>>(btot, bofs, E);
    emit_kernel<<<NEB, 256, 0, stream>>>(adj_row, adj_col, adj_val, sofs, bofs, egs, E, chunk);
    binsort2_kernel<<<NBK, 1024, 0, stream>>>(egs, bofs, row_ptr, eg, E);
    gatherb_kernel<0><<<(NN + 3) / 4, 256, 0, stream>>>(row_ptr, eg, emb_bf, embedding, accA_bf, (float*)nullptr);
    gatherb_kernel<1><<<(NN + 3) / 4, 256, 0, stream>>>(row_ptr, eg, accA_bf, embedding, (u16*)nullptr, out0);

    // ---- Part 2: LineConv (MFMA chain); final GEMM fuses out1 = sess + s1 + s2 ----
    sess_pool_kernel<<<BB, 128, 0, stream>>>(session_item, embedding, session_len, sess, sessT);
    mm_mfma_kernel<1, 0, 0><<<64, 256, 0, stream>>>(A_bf, sessT, t1T, (float*)nullptr, (const float*)nullptr, (const float*)nullptr);
    mm_mfma_kernel<1, 1, 0><<<64, 256, 0, stream>>>(D_bf, t1T, s1T, s1, (const float*)nullptr, (const float*)nullptr);
    mm_mfma_kernel<1, 0, 0><<<64, 256, 0, stream>>>(A_bf, s1T, t2T, (float*)nullptr, (const float*)nullptr, (const float*)nullptr);
    mm_mfma_kernel<0, 1, 1><<<64, 256, 0, stream>>>(D_bf, t2T, (u16*)nullptr, out1, sess, s1);

    // ---- Part 3: GNN reassociated, one dispatch over all 1024 sessions ----
    gnn_tail_kernel<<<BB, 512, 0, stream>>>(hidden, A_gnn, alias_pos,
                                            WcT_bf, w_hh_bf, uf, out2);
}

// Round 16
// 310.272 us; speedup vs baseline: 1.0189x; 1.0189x over previous
//
#include <hip/hip_runtime.h>

#define EMB 128
#define NN 50000
#define BB 1024
#define LL 50
#define NBK 49     // ceil(NN/1024) buckets
#define NEB 512    // emit/count chunks
#define NCONV 2048 // prep convert blocks; blocks >= NCONV do wcomb/uf folds

typedef float f32x4 __attribute__((ext_vector_type(4)));
typedef float f32x2 __attribute__((ext_vector_type(2)));
typedef unsigned short u16;
typedef unsigned int u32;
typedef unsigned long long u64;
typedef u16 u16x4 __attribute__((ext_vector_type(4)));
typedef u32 u32x4 __attribute__((ext_vector_type(4)));
typedef short bf16x8 __attribute__((ext_vector_type(8)));   // 8 bf16 in 4 VGPRs

__device__ __forceinline__ float u2f(u16 u) {
    union { unsigned int i; float f; } v; v.i = ((unsigned int)u) << 16; return v.f;
}
__device__ __forceinline__ u16 f2b(float f) {
    union { float f; unsigned int i; } v; v.f = f;
    unsigned int i = v.i;
    return (u16)((i + 0x7FFFu + ((i >> 16) & 1u)) >> 16);   // RNE
}
__device__ __forceinline__ float lo2f(u32 w) { return u2f((u16)(w & 0xffffu)); }
__device__ __forceinline__ float hi2f(u32 w) { return u2f((u16)(w >> 16)); }
__device__ __forceinline__ float sigmoidf_(float x) { return 1.f / (1.f + __expf(-x)); }
__device__ __forceinline__ float tanhf_(float x) {
    float e = __expf(-2.f * x);
    return (1.f - e) / (1.f + e);
}

// ============ prep: converts + per-(chunk,bucket) counts + Wcomb/uf folds ============
// uf[d][12]: 0..2 = u1{r,i,n}, 3..5 = u2{r,i,n}, 6 = u3r+b_hh[d], 7 = u3i+b_hh[128+d],
//            8 = u3n, 9 = b_hh[256+d] (bnh), 10..11 = 0.
__global__ __launch_bounds__(256) void prep_kernel(
    const float* __restrict__ emb, const float* __restrict__ A, const float* __restrict__ D,
    const float* __restrict__ whh,
    u16* __restrict__ emb_bf, u16* __restrict__ A_bf, u16* __restrict__ D_bf,
    u16* __restrict__ whh_bf,
    const int* __restrict__ rowi, int* __restrict__ bcnt,
    const float* __restrict__ w_ih, const float* __restrict__ W_in, const float* __restrict__ W_out,
    const float* __restrict__ b_in, const float* __restrict__ b_out,
    const float* __restrict__ b_iah, const float* __restrict__ b_oah, const float* __restrict__ b_ih,
    const float* __restrict__ b_hh,
    u16* __restrict__ WcT_bf, float* __restrict__ uf,
    int E, int chunk)
{
    __shared__ int lc[NBK];
    __shared__ float wrow[256];
    __shared__ float red[3][256];
    int tid = threadIdx.x;

    if (blockIdx.x >= NCONV) {
        // ---- wcomb + uf block: d = blockIdx.x - NCONV in [0,384) ----
        int d = blockIdx.x - NCONV;
        int c = tid;
        wrow[c] = w_ih[d * 256 + c];
        __syncthreads();
        const float* W = (c < 128) ? W_in : W_out;
        const float* wr = wrow + ((c < 128) ? 0 : 128);
        int cc = c & 127;
        float acc = 0.f;
#pragma unroll 4
        for (int j = 0; j < 128; j++) acc += wr[j] * W[j * 128 + cc];
        WcT_bf[d * 256 + c] = f2b(acc);
        // uf partials (coalesced: all of w_ih row d already in LDS)
        float p1 = (c < 128) ? b_in[c] * wrow[c] : 0.f;
        float p2 = (c >= 128) ? b_out[cc] * wrow[c] : 0.f;
        float p3 = (c < 128) ? b_iah[c] * wrow[c] : b_oah[cc] * wrow[c];
        red[0][c] = p1; red[1][c] = p2; red[2][c] = p3;
        __syncthreads();
        for (int off = 128; off > 0; off >>= 1) {
            if (c < off) {
                red[0][c] += red[0][c + off];
                red[1][c] += red[1][c + off];
                red[2][c] += red[2][c + off];
            }
            __syncthreads();
        }
        if (c == 0) {
            int g = d >> 7, dd = d & 127;
            float u1v = red[0][0];
            float u2v = red[1][0];
            float u3v = red[2][0] + b_ih[d];
            uf[dd * 12 + g] = u1v;
            uf[dd * 12 + 3 + g] = u2v;
            if (g == 0)      uf[dd * 12 + 6] = u3v + b_hh[dd];
            else if (g == 1) uf[dd * 12 + 7] = u3v + b_hh[128 + dd];
            else {
                uf[dd * 12 + 8]  = u3v;
                uf[dd * 12 + 9]  = b_hh[256 + dd];
                uf[dd * 12 + 10] = 0.f;
                uf[dd * 12 + 11] = 0.f;
            }
        }
        return;
    }

    int gid = blockIdx.x * 256 + tid;
    int stride = NCONV * 256;
    if (blockIdx.x < NEB) {
        if (tid < NBK) lc[tid] = 0;
        __syncthreads();
        int beg = blockIdx.x * chunk, end = min(E, beg + chunk);
        for (int e = beg + tid; e < end; e += 256)
            atomicAdd(&lc[rowi[e] >> 10], 1);
        __syncthreads();
        if (tid < NBK) bcnt[blockIdx.x * NBK + tid] = lc[tid];
    }
    for (int i = gid; i < 1600000; i += stride) {
        f32x4 v = *(const f32x4*)(emb + (size_t)i * 4);
        u16x4 p;
#pragma unroll
        for (int t = 0; t < 4; t++) p[t] = f2b(v[t]);
        *(u16x4*)(emb_bf + (size_t)i * 4) = p;
    }
    for (int i = gid; i < 2146304; i += stride) {
        const float* s; u16* d; int off;
        if (i < 1048576)      { s = A;   d = A_bf;   off = i; }
        else if (i < 2097152) { s = D;   d = D_bf;   off = i - 1048576; }
        else                  { s = whh; d = whh_bf; off = i - 2097152; }
        d[off] = f2b(s[off]);
    }
}

// per-bucket exclusive scan over chunks -> LOCAL bases + bucket totals
__global__ __launch_bounds__(512) void bktscan_kernel(
    const int* __restrict__ bcnt, int* __restrict__ sofs, int* __restrict__ btot)
{
    __shared__ int ps[512];
    int k = blockIdx.x, t = threadIdx.x;
    int c = bcnt[t * NBK + k];
    ps[t] = c; __syncthreads();
    for (int off = 1; off < 512; off <<= 1) {
        int v = (t >= off) ? ps[t - off] : 0;
        __syncthreads();
        ps[t] += v; __syncthreads();
    }
    sofs[t * NBK + k] = ps[t] - c;
    if (t == 511) btot[k] = ps[511];
}

__global__ __launch_bounds__(64) void btotal_kernel(
    const int* __restrict__ btot, int* __restrict__ bofs, int E)
{
    if (threadIdx.x == 0) {
        int run = 0;
        for (int k = 0; k < NBK; k++) { bofs[k] = run; run += btot[k]; }
        bofs[NBK] = E;
    }
}

__global__ __launch_bounds__(256) void emit_kernel(
    const int* __restrict__ rowi, const int* __restrict__ coli, const float* __restrict__ val,
    const int* __restrict__ sofs, const int* __restrict__ bofs,
    u64* __restrict__ egs, int E, int chunk)
{
    __shared__ int cur[NBK];
    int b = blockIdx.x, tid = threadIdx.x;
    if (tid < NBK) cur[tid] = bofs[tid] + sofs[b * NBK + tid];
    __syncthreads();
    int beg = b * chunk, end = min(E, beg + chunk);
    for (int e = beg + tid; e < end; e += 256) {
        int r = rowi[e];
        int slot = atomicAdd(&cur[r >> 10], 1);
        u64 entry = ((u64)(u32)(r & 1023) << 32)
                  | (u64)((u32)(u16)coli[e] | ((u32)f2b(val[e]) << 16));
        egs[slot] = entry;
    }
}

__global__ __launch_bounds__(1024) void binsort2_kernel(
    const u64* __restrict__ egs, const int* __restrict__ bofs,
    int* __restrict__ row_ptr, u32* __restrict__ eg, int E)
{
    __shared__ int cnt_s[1024];
    __shared__ int ps[1024];
    int k = blockIdx.x, tid = threadIdx.x;
    int r0 = k << 10;
    int beg = bofs[k], end = bofs[k + 1];
    cnt_s[tid] = 0;
    __syncthreads();
    for (int i = beg + tid; i < end; i += 1024)
        atomicAdd(&cnt_s[(int)(egs[i] >> 32)], 1);
    __syncthreads();
    int v = cnt_s[tid];
    ps[tid] = v; __syncthreads();
    for (int off = 1; off < 1024; off <<= 1) {
        int t = (tid >= off) ? ps[tid - off] : 0;
        __syncthreads();
        ps[tid] += t; __syncthreads();
    }
    int ex = beg + ps[tid] - v;
    if (r0 + tid <= NN) row_ptr[r0 + tid] = ex;
    if (k == NBK - 1 && tid == 1023) row_ptr[NN] = E;
    cnt_s[tid] = ex;
    __syncthreads();
    for (int i = beg + tid; i < end; i += 1024) {
        u64 entry = egs[i];
        int rlo = (int)(entry >> 32);
        int p = atomicAdd(&cnt_s[rlo], 1);
        eg[p] = (u32)entry;
    }
}

// One wave per row. 64 lanes = 4 edge-groups x 16 feature-blocks.
template<int FUSE>
__global__ __launch_bounds__(256) void gatherb_kernel(
    const int* __restrict__ row_ptr, const u32* __restrict__ eg,
    const u16* __restrict__ src, const float* __restrict__ emb0,
    u16* __restrict__ dst_bf, float* __restrict__ dst_f)
{
    int wave = threadIdx.x >> 6;
    int lane = threadIdx.x & 63;
    int g  = lane >> 4;          // edge slot within chunk-of-4
    int fl = lane & 15;          // feature block: features fl*8 .. fl*8+7
    int r = blockIdx.x * 4 + wave;
    if (r >= NN) return;
    int beg = row_ptr[r], end = row_ptr[r + 1];

    float acc[8];
#pragma unroll
    for (int t = 0; t < 8; t++) acc[t] = 0.f;

    if (beg < end) {
        int last = end - 1;
        int npair = (end - beg + 7) >> 3;
        u32 pkA = eg[min(beg + g, last)];
        u32 pkB = eg[min(beg + 4 + g, last)];
        float vA = (beg + g     < end) ? u2f((u16)(pkA >> 16)) : 0.f;
        float vB = (beg + 4 + g < end) ? u2f((u16)(pkB >> 16)) : 0.f;
        u32x4 xA = *(const u32x4*)(src + ((pkA & 0xffffu) << 7) + (fl << 3));
        u32x4 xB = *(const u32x4*)(src + ((pkB & 0xffffu) << 7) + (fl << 3));
        pkA = eg[min(beg + 8  + g, last)];
        pkB = eg[min(beg + 12 + g, last)];

        int e = beg;
        for (int p = 0; p < npair; p++) {
            float cvA = vA, cvB = vB;
            u32x4 cxA = xA, cxB = xB;
            int eN = e + 8;
            vA = (eN + g     < end) ? u2f((u16)(pkA >> 16)) : 0.f;
            vB = (eN + 4 + g < end) ? u2f((u16)(pkB >> 16)) : 0.f;
            xA = *(const u32x4*)(src + ((pkA & 0xffffu) << 7) + (fl << 3));
            xB = *(const u32x4*)(src + ((pkB & 0xffffu) << 7) + (fl << 3));
            int eS = e + 16;
            pkA = eg[min(eS + g, last)];
            pkB = eg[min(eS + 4 + g, last)];
#pragma unroll
            for (int t = 0; t < 4; t++) {
                acc[2 * t]     += cvA * lo2f(cxA[t]);
                acc[2 * t + 1] += cvA * hi2f(cxA[t]);
            }
#pragma unroll
            for (int t = 0; t < 4; t++) {
                acc[2 * t]     += cvB * lo2f(cxB[t]);
                acc[2 * t + 1] += cvB * hi2f(cxB[t]);
            }
            e += 8;
        }
    }

#pragma unroll
    for (int t = 0; t < 8; t++) {
        acc[t] += __shfl_xor(acc[t], 16);
        acc[t] += __shfl_xor(acc[t], 32);
    }

    if (lane < 16) {
        if (FUSE) {
            u32x4 s = *(const u32x4*)(src + ((u32)r << 7) + (lane << 3));
            const float* e0p = emb0 + ((size_t)r << 7) + (lane << 3);
            f32x4 e0a = *(const f32x4*)e0p;
            f32x4 e0b = *(const f32x4*)(e0p + 4);
            f32x4 o0, o1;
#pragma unroll
            for (int t = 0; t < 2; t++) {
                o0[2 * t]     = acc[2 * t]     + e0a[2 * t]     + lo2f(s[t]);
                o0[2 * t + 1] = acc[2 * t + 1] + e0a[2 * t + 1] + hi2f(s[t]);
                o1[2 * t]     = acc[4 + 2 * t]     + e0b[2 * t]     + lo2f(s[2 + t]);
                o1[2 * t + 1] = acc[4 + 2 * t + 1] + e0b[2 * t + 1] + hi2f(s[2 + t]);
            }
            float* dp = dst_f + ((size_t)r << 7) + (lane << 3);
            *(f32x4*)dp = o0;
            *(f32x4*)(dp + 4) = o1;
        } else {
            u32x4 w;
#pragma unroll
            for (int t = 0; t < 4; t++)
                w[t] = (u32)f2b(acc[2 * t]) | ((u32)f2b(acc[2 * t + 1]) << 16);
            *(u32x4*)(dst_bf + ((size_t)r << 7) + (lane << 3)) = w;
        }
    }
}

// ================= Part 2: LineConv (bf16 MFMA chain) =================
__global__ __launch_bounds__(128) void sess_pool_kernel(
    const int* __restrict__ items, const float* __restrict__ emb,
    const float* __restrict__ slen, float* __restrict__ sess, u16* __restrict__ sessT)
{
    int b = blockIdx.x, d = threadIdx.x;
    const int* it = items + b * LL;
    float acc = 0.f;
    for (int l = 0; l < LL; l++) {
        int idx = it[l];
        if (idx > 0) acc += emb[(size_t)(idx - 1) * EMB + d];
    }
    float v = acc / slen[b];
    sess[b * EMB + d] = v;
    sessT[d * BB + b] = f2b(v);
}

// C[1024,128] = M_bf @ Xt_bf^T. 64 blocks x 4 waves; wave owns (16-row tile, 2 col-tiles).
// FADD: epilogue writes C_f = acc + add1 + add2 (fuses the final out1 sum).
template<int WT, int WF, int FADD>
__global__ __launch_bounds__(256) void mm_mfma_kernel(
    const u16* __restrict__ M_bf, const u16* __restrict__ Xt_bf,
    u16* __restrict__ Ct_bf, float* __restrict__ C_f,
    const float* __restrict__ add1, const float* __restrict__ add2)
{
    int tid = threadIdx.x;
    int wv = tid >> 6, lane = tid & 63, cl = lane & 15, kg = lane >> 4;
    int rbase = blockIdx.x * 16;
    f32x4 acc[2];
    acc[0] = (f32x4)0.f; acc[1] = (f32x4)0.f;
    const u16* arow = M_bf + (size_t)(rbase + cl) * BB + kg * 8;
    const u16* brow = Xt_bf + (size_t)(wv * 32 + cl) * BB + kg * 8;
#pragma unroll 4
    for (int k0 = 0; k0 < BB; k0 += 32) {
        bf16x8 a  = *(const bf16x8*)(arow + k0);
        bf16x8 b0 = *(const bf16x8*)(brow + k0);
        bf16x8 b1 = *(const bf16x8*)(brow + (size_t)16 * BB + k0);
        acc[0] = __builtin_amdgcn_mfma_f32_16x16x32_bf16(a, b0, acc[0], 0, 0, 0);
        acc[1] = __builtin_amdgcn_mfma_f32_16x16x32_bf16(a, b1, acc[1], 0, 0, 0);
    }
#pragma unroll
    for (int nt = 0; nt < 2; nt++) {
        int col = (wv * 2 + nt) * 16 + cl;
#pragma unroll
        for (int j = 0; j < 4; j++) {
            int row = rbase + kg * 4 + j;
            size_t ix = (size_t)row * EMB + col;
            if (WF) {
                float v = acc[nt][j];
                if (FADD) v += add1[ix] + add2[ix];
                C_f[ix] = v;
            }
            if (WT) Ct_bf[(size_t)col * BB + row] = f2b(acc[nt][j]);
        }
    }
}

// ========== Part 3: GNN, reassociated; register-lean Phase 2 + compact epilogue ==========
// Phase 0: stage hidden (Hs swz + HsT strided) and A_cat (As swz) once; rowsums -> rcs.
// Phase 1: M2 = A_cat @ hidden  ([64 x 256], K=64) -> M2s (overlays As+HsT).
// Phase 2: {ks -> g -> mt}, one a + one bw live. Epilogue: sched_barrier then 3 f32x4
// loads from uf[dl*12] (bias-folds pre-packed in prep). 8-wave monolithic with natural
// allocation is the structural optimum (R6/R7/R9/R12/R13/R15 all regressed).
__global__ __launch_bounds__(512) void gnn_tail_kernel(
    const float* __restrict__ hidden,
    const float* __restrict__ A_gnn, const int* __restrict__ alias_pos,
    const u16* __restrict__ WcT_bf, const u16* __restrict__ w_hh_bf,
    const float* __restrict__ uf,
    float* __restrict__ hy)
{
    __shared__ __attribute__((aligned(16))) u16 smem[25600];   // 51.2 KB
    u16* Hs  = smem;            // [64][128] bf16 swz
    u16* As  = smem + 8192;     // [64][128] bf16 swz (cols 0-63 A_in, 64-127 A_out)
    u16* HsT = smem + 16384;    // [128][72] bf16 strided (144B rows)
    u16* M2s = smem + 8192;     // [64][256] bf16 swz, overlays As+HsT[:8192] after Phase 1
    __shared__ float rcs[64][2];

    int b = blockIdx.x;
    int tid = threadIdx.x;
    int wv = tid >> 6, lane = tid & 63, cl = lane & 15, kg = lane >> 4;

    // ---- Phase 0: prefetch A_io + hidden into regs, then write LDS ----
    int pr_row[4], pr_c4[4], ppos[4];
#pragma unroll
    for (int it = 0; it < 4; it++) {
        int i = tid + it * 512;
        pr_row[it] = i >> 5; pr_c4[it] = i & 31;
        ppos[it] = (pr_row[it] < LL) ? alias_pos[b * LL + pr_row[it]] : 0;
    }
    float av[4][4];
#pragma unroll
    for (int it = 0; it < 4; it++) {
        const float* ar = A_gnn + ((size_t)b * LL + ppos[it]) * (2 * LL);
#pragma unroll
        for (int t = 0; t < 4; t++) {
            int jp = pr_c4[it] * 4 + t;
            int col = (jp < 64) ? jp : (50 + (jp - 64));
            int ok = (pr_row[it] < LL) && ((jp < 64) ? (jp < LL) : ((jp - 64) < LL));
            av[it][t] = ok ? ar[col] : 0.f;
        }
    }
    const float* hsrc = hidden + (size_t)b * LL * EMB;
#pragma unroll
    for (int it = 0; it < 4; it++) {
        u16x4 p;
#pragma unroll
        for (int t = 0; t < 4; t++) p[t] = f2b(av[it][t]);
        *(u16x4*)((char*)As + pr_row[it] * 256 + ((pr_c4[it] * 8) ^ ((pr_row[it] & 7) << 4))) = p;
    }
#pragma unroll
    for (int i2 = 0; i2 < 4; i2++) {
        int lin = i2 * 512 + tid;
        int hrow = lin >> 5, hc4 = lin & 31;
        f32x4 v = (hrow < LL) ? *(const f32x4*)(hsrc + hrow * 128 + hc4 * 4) : (f32x4)0.f;
        u16x4 q;
#pragma unroll
        for (int t = 0; t < 4; t++) q[t] = f2b(v[t]);
        *(u16x4*)((char*)Hs + hrow * 256 + ((hc4 * 8) ^ ((hrow & 7) << 4))) = q;
    }
    // HsT: thread handles column c, 4 rows rg*4..rg*4+3 -> single u16x4 write
#pragma unroll
    for (int i2 = 0; i2 < 4; i2++) {
        int idx = i2 * 512 + tid;
        int c = idx & 127, rg = idx >> 7;
        int r0 = rg * 4;
        u16x4 p = (u16x4)0;
#pragma unroll
        for (int k = 0; k < 4; k++) {
            int row = r0 + k;
            p[k] = (row < LL) ? f2b(hsrc[row * 128 + c]) : (u16)0;
        }
        *(u16x4*)&HsT[c * 72 + r0] = p;
    }
    __syncthreads();   // bar1: staging done

    // rowsums (waves 0-1 only; consumed after bar3)
    if (tid < 128) {
        int row = tid >> 1, hf = tid & 1;
        float s = 0.f;
#pragma unroll
        for (int c4 = 0; c4 < 16; c4++) {
            u16x4 v = *(const u16x4*)((const char*)As + row * 256 +
                        ((hf * 128 + c4 * 8) ^ ((row & 7) << 4)));
            s += u2f(v[0]) + u2f(v[1]) + u2f(v[2]) + u2f(v[3]);
        }
        rcs[row][hf] = s;
    }

    // ---- Phase 1: M2 = A_cat @ hidden; wave = (h = wv>>2, ct = wv&3) ----
    {
        int h = wv >> 2, ct = wv & 3;
        f32x4 m2acc[4][2];
#pragma unroll
        for (int mt = 0; mt < 4; mt++) { m2acc[mt][0] = (f32x4)0.f; m2acc[mt][1] = (f32x4)0.f; }
#pragma unroll
        for (int ks = 0; ks < 2; ks++) {
            bf16x8 bb[2];
#pragma unroll
            for (int nt = 0; nt < 2; nt++) {
                int c = ct * 32 + nt * 16 + cl;
                bb[nt] = *(const bf16x8*)&HsT[c * 72 + ks * 32 + kg * 8];
            }
#pragma unroll
            for (int mt = 0; mt < 4; mt++) {
                int mr = mt * 16 + cl;
                bf16x8 aa = *(const bf16x8*)((const char*)As + mr * 256 +
                             ((h * 128 + ks * 64 + kg * 16) ^ ((mr & 7) << 4)));
#pragma unroll
                for (int nt = 0; nt < 2; nt++)
                    m2acc[mt][nt] = __builtin_amdgcn_mfma_f32_16x16x32_bf16(aa, bb[nt], m2acc[mt][nt], 0, 0, 0);
            }
        }
        __syncthreads();   // bar2: all P1 reads (and rcs reads of As) done
#pragma unroll
        for (int mt = 0; mt < 4; mt++)
#pragma unroll
            for (int nt = 0; nt < 2; nt++) {
                int kcol = h * 128 + ct * 32 + nt * 16 + cl;
#pragma unroll
                for (int j = 0; j < 4; j++) {
                    int row = mt * 16 + kg * 4 + j;
                    *(u16*)((char*)M2s + row * 512 + ((kcol * 2) ^ ((row & 7) << 4))) =
                        f2b(m2acc[mt][nt][j]);
                }
            }
    }
    __syncthreads();   // bar3: M2s ready

    // ---- Phase 2: gi = M2 @ WcombT (K=256) + gh = hidden @ w_hh^T (K=128); d = wv*16+cl ----
    // Register-lean order: {ks -> g -> mt}; one a + one bw live; A re-read per gate.
    int dl = wv * 16 + cl;
    f32x4 accR[4], accI[4], accN1[4], accN2[4];
#pragma unroll
    for (int mt = 0; mt < 4; mt++) {
        accR[mt] = (f32x4)0.f; accI[mt] = (f32x4)0.f;
        accN1[mt] = (f32x4)0.f; accN2[mt] = (f32x4)0.f;
    }

#pragma unroll
    for (int ks = 0; ks < 8; ks++) {
        {
            bf16x8 bw = *(const bf16x8*)(WcT_bf + (size_t)dl * 256 + ks * 32 + kg * 8);
#pragma unroll
            for (int mt = 0; mt < 4; mt++) {
                int mr = mt * 16 + cl;
                bf16x8 a = *(const bf16x8*)((const char*)M2s + mr * 512 +
                             ((ks * 64 + kg * 16) ^ ((mr & 7) << 4)));
                accR[mt] = __builtin_amdgcn_mfma_f32_16x16x32_bf16(a, bw, accR[mt], 0, 0, 0);
            }
        }
        {
            bf16x8 bw = *(const bf16x8*)(WcT_bf + (size_t)(128 + dl) * 256 + ks * 32 + kg * 8);
#pragma unroll
            for (int mt = 0; mt < 4; mt++) {
                int mr = mt * 16 + cl;
                bf16x8 a = *(const bf16x8*)((const char*)M2s + mr * 512 +
                             ((ks * 64 + kg * 16) ^ ((mr & 7) << 4)));
                accI[mt] = __builtin_amdgcn_mfma_f32_16x16x32_bf16(a, bw, accI[mt], 0, 0, 0);
            }
        }
        {
            bf16x8 bw = *(const bf16x8*)(WcT_bf + (size_t)(256 + dl) * 256 + ks * 32 + kg * 8);
#pragma unroll
            for (int mt = 0; mt < 4; mt++) {
                int mr = mt * 16 + cl;
                bf16x8 a = *(const bf16x8*)((const char*)M2s + mr * 512 +
                             ((ks * 64 + kg * 16) ^ ((mr & 7) << 4)));
                accN1[mt] = __builtin_amdgcn_mfma_f32_16x16x32_bf16(a, bw, accN1[mt], 0, 0, 0);
            }
        }
    }
#pragma unroll
    for (int ks = 0; ks < 4; ks++) {
        {
            bf16x8 bw = *(const bf16x8*)(w_hh_bf + (size_t)dl * 128 + ks * 32 + kg * 8);
#pragma unroll
            for (int mt = 0; mt < 4; mt++) {
                int mr = mt * 16 + cl;
                bf16x8 a = *(const bf16x8*)((const char*)Hs + mr * 256 +
                             ((ks * 64 + kg * 16) ^ ((mr & 7) << 4)));
                accR[mt] = __builtin_amdgcn_mfma_f32_16x16x32_bf16(a, bw, accR[mt], 0, 0, 0);
            }
        }
        {
            bf16x8 bw = *(const bf16x8*)(w_hh_bf + (size_t)(128 + dl) * 128 + ks * 32 + kg * 8);
#pragma unroll
            for (int mt = 0; mt < 4; mt++) {
                int mr = mt * 16 + cl;
                bf16x8 a = *(const bf16x8*)((const char*)Hs + mr * 256 +
                             ((ks * 64 + kg * 16) ^ ((mr & 7) << 4)));
                accI[mt] = __builtin_amdgcn_mfma_f32_16x16x32_bf16(a, bw, accI[mt], 0, 0, 0);
            }
        }
        {
            bf16x8 bw = *(const bf16x8*)(w_hh_bf + (size_t)(256 + dl) * 128 + ks * 32 + kg * 8);
#pragma unroll
            for (int mt = 0; mt < 4; mt++) {
                int mr = mt * 16 + cl;
                bf16x8 a = *(const bf16x8*)((const char*)Hs + mr * 256 +
                             ((ks * 64 + kg * 16) ^ ((mr & 7) << 4)));
                accN2[mt] = __builtin_amdgcn_mfma_f32_16x16x32_bf16(a, bw, accN2[mt], 0, 0, 0);
            }
        }
    }

    // ---- GRU gates: loads fenced out of the MFMA region ----
    __builtin_amdgcn_sched_barrier(0);
    {
        const f32x4* ufp = (const f32x4*)(uf + dl * 12);
        f32x4 U0 = ufp[0];   // u1r u1i u1n u2r
        f32x4 U1 = ufp[1];   // u2i u2n u3r' u3i'
        f32x4 U2 = ufp[2];   // u3n bnh 0 0
        float* hyb = hy + (size_t)b * LL * 128 + dl;
#pragma unroll
        for (int mt = 0; mt < 4; mt++)
#pragma unroll
            for (int j = 0; j < 4; j++) {
                int row = mt * 16 + kg * 4 + j;
                if (row >= LL) continue;
                float cr = rcs[row][0], dr = rcs[row][1];
                float pr  = accR[mt][j]  + cr * U0[0] + dr * U0[3] + U1[2];
                float pi  = accI[mt][j]  + cr * U0[1] + dr * U1[0] + U1[3];
                float pn1 = accN1[mt][j] + cr * U0[2] + dr * U1[1] + U2[0];
                float pn2 = accN2[mt][j] + U2[1];
                float rg = sigmoidf_(pr);
                float ig = sigmoidf_(pi);
                float ng = tanhf_(pn1 + rg * pn2);
                u16 hb = *(const u16*)((const char*)Hs + row * 256 + ((dl * 2) ^ ((row & 7) << 4)));
                float h = u2f(hb);
                hyb[row * 128] = ng + ig * (h - ng);
            }
    }
}

extern "C" void kernel_launch(void* const* d_in, const int* in_sizes, int n_in,
                              void* d_out, int out_size, void* d_ws, size_t ws_size,
                              hipStream_t stream) {
    (void)n_in; (void)out_size; (void)ws_size;
    const int*   adj_row      = (const int*)d_in[0];
    const int*   adj_col      = (const int*)d_in[1];
    const float* adj_val      = (const float*)d_in[2];
    const float* embedding    = (const float*)d_in[3];
    const int*   session_item = (const int*)d_in[4];
    const float* session_len  = (const float*)d_in[5];
    const float* Dm           = (const float*)d_in[6];
    const float* A_sess       = (const float*)d_in[7];
    const float* A_gnn        = (const float*)d_in[8];
    const int*   alias_pos    = (const int*)d_in[9];
    const float* hidden       = (const float*)d_in[10];
    const float* W_in         = (const float*)d_in[11];
    const float* b_in         = (const float*)d_in[12];
    const float* W_out        = (const float*)d_in[13];
    const float* b_out        = (const float*)d_in[14];
    const float* w_ih         = (const float*)d_in[15];
    const float* b_ih         = (const float*)d_in[16];
    const float* w_hh         = (const float*)d_in[17];
    const float* b_hh         = (const float*)d_in[18];
    const float* b_iah        = (const float*)d_in[19];
    const float* b_oah        = (const float*)d_in[20];
    const int E = in_sizes[0];

    float* out0 = (float*)d_out;
    float* out1 = out0 + 6400000;
    float* out2 = out1 + 131072;

    float* ws = (float*)d_ws;
    u16*  emb_bf  = (u16*)ws;                    // [0, 3.2M) live through gathers
    int*  bcnt  = (int*)(ws + 3200000);          // scratch under accA region
    int*  sofs  = (int*)(ws + 3230000);
    int*  btot  = (int*)(ws + 3260000);
    u16*  accA_bf = (u16*)(ws + 3200000);        // [3.2M, 6.4M) gather<0> out
    u32*  eg    = (u32*)(ws + 6400000);          // [6.4M, 8.0M)
    u64*  egs   = (u64*)(ws + 8000000);          // [8.0M, 11.2M)
    float* sess  = ws + 11200000;
    u16*   sessT = (u16*)(ws + 11350000);
    u16*   t1T   = (u16*)(ws + 11400000);
    u16*   s1T   = (u16*)(ws + 11450000);
    u16*   t2T   = (u16*)(ws + 11500000);
    float* s1    = ws + 11550000;
    u16*   A_bf  = (u16*)(ws + 11850000);
    u16*   D_bf  = (u16*)(ws + 12400000);
    int*   row_ptr = (int*)(ws + 12950000);
    int*   bofs    = row_ptr + NN + 1;
    u16* WcT_bf    = (u16*)(ws + 13107200);      // [384][256] bf16
    u16* w_hh_bf   = WcT_bf + 98304;             // [384][128] bf16
    float* uf      = (float*)(w_hh_bf + 49152);  // [128][12] f32 bias folds

    int chunk = (E + NEB - 1) / NEB;

    // ---- prep: converts + chunked bucket counts + weight/bias folds (tail blocks) ----
    prep_kernel<<<NCONV + 384, 256, 0, stream>>>(embedding, A_sess, Dm, w_hh,
                                          emb_bf, A_bf, D_bf, w_hh_bf,
                                          adj_row, bcnt,
                                          w_ih, W_in, W_out, b_in, b_out, b_iah, b_oah, b_ih, b_hh,
                                          WcT_bf, uf,
                                          E, chunk);

    // ---- Part 1: bucket sort + 2 bf16 gather layers ----
    bktscan_kernel<<<NBK, 512, 0, stream>>>(bcnt, sofs, btot);
    btotal_kernel<<<1, 64, 0, stream>>>(btot, bofs, E);
    emit_kernel<<<NEB, 256, 0, stream>>>(adj_row, adj_col, adj_val, sofs, bofs, egs, E, chunk);
    binsort2_kernel<<<NBK, 1024, 0, stream>>>(egs, bofs, row_ptr, eg, E);
    gatherb_kernel<0><<<(NN + 3) / 4, 256, 0, stream>>>(row_ptr, eg, emb_bf, embedding, accA_bf, (float*)nullptr);
    gatherb_kernel<1><<<(NN + 3) / 4, 256, 0, stream>>>(row_ptr, eg, accA_bf, embedding, (u16*)nullptr, out0);

    // ---- Part 2: LineConv (MFMA chain); final GEMM fuses out1 = sess + s1 + s2 ----
    sess_pool_kernel<<<BB, 128, 0, stream>>>(session_item, embedding, session_len, sess, sessT);
    mm_mfma_kernel<1, 0, 0><<<64, 256, 0, stream>>>(A_bf, sessT, t1T, (float*)nullptr, (const float*)nullptr, (const float*)nullptr);
    mm_mfma_kernel<1, 1, 0><<<64, 256, 0, stream>>>(D_bf, t1T, s1T, s1, (const float*)nullptr, (const float*)nullptr);
    mm_mfma_kernel<1, 0, 0><<<64, 256, 0, stream>>>(A_bf, s1T, t2T, (float*)nullptr, (const float*)nullptr, (const float*)nullptr);
    mm_mfma_kernel<0, 1, 1><<<64, 256, 0, stream>>>(D_bf, t2T, (u16*)nullptr, out1, sess, s1);

    // ---- Part 3: GNN reassociated, one dispatch over all 1024 sessions ----
    gnn_tail_kernel<<<BB, 512, 0, stream>>>(hidden, A_gnn, alias_pos,
                                            WcT_bf, w_hh_bf, uf, out2);
}